// Round 1
// baseline (811.225 us; speedup 1.0000x reference)
//
#include <hip/hip_runtime.h>
#include <hip/hip_fp16.h>

#define B_ 256
#define T_ 200
#define H_ 256
#define G3 768            // 3*H
#define NV 50001          // V+1

using half2v = __attribute__((ext_vector_type(2))) _Float16;

union U32H2 { unsigned int u; half2v h; };

__device__ __forceinline__ float fdot2(half2v a, half2v b, float c) {
  return __builtin_amdgcn_fdot2(a, b, c, false);
}
__device__ __forceinline__ float sigmoidf_(float x) {
  return 1.f / (1.f + __expf(-x));
}
__device__ __forceinline__ float tanhf_(float x) {
  float ax = fabsf(x);
  float e = __expf(-2.f * ax);
  float t = (1.f - e) / (1.f + e);
  return copysignf(t, x);
}

// Load this thread's slice of a [256 x 768] fp32 weight matrix into registers
// as fp16 pairs along K. Thread owns k in [kc*128, kc*128+128), col g*256+j.
__device__ __forceinline__ void load_w(const float* __restrict__ w, int kc, int j,
                                       half2v W[3][64]) {
  const float* wb = w + (size_t)(kc * 128) * G3 + j;
#pragma unroll
  for (int p = 0; p < 64; ++p) {
#pragma unroll
    for (int gg = 0; gg < 3; ++gg) {
      float w0 = wb[(size_t)(2 * p) * G3 + gg * 256];
      float w1 = wb[(size_t)(2 * p + 1) * G3 + gg * 256];
      half2v h2;
      h2.x = (_Float16)w0;
      h2.y = (_Float16)w1;
      W[gg][p] = h2;
    }
  }
}

// Phase A: 192 v_dot2_f32_f16 against packed fp16 vector in LDS (wave-uniform
// addresses -> broadcast reads).
__device__ __forceinline__ void dot_phase(const half2v (&W)[3][64],
                                          const unsigned int* xp, int kc,
                                          float& az, float& ar, float& ah) {
#pragma unroll
  for (int p4 = 0; p4 < 16; ++p4) {
    uint4 hv = *((const uint4*)(xp + kc * 64 + p4 * 4));
    U32H2 c0, c1, c2, c3;
    c0.u = hv.x; c1.u = hv.y; c2.u = hv.z; c3.u = hv.w;
    az = fdot2(W[0][4 * p4 + 0], c0.h, az);
    ar = fdot2(W[1][4 * p4 + 0], c0.h, ar);
    ah = fdot2(W[2][4 * p4 + 0], c0.h, ah);
    az = fdot2(W[0][4 * p4 + 1], c1.h, az);
    ar = fdot2(W[1][4 * p4 + 1], c1.h, ar);
    ah = fdot2(W[2][4 * p4 + 1], c1.h, ah);
    az = fdot2(W[0][4 * p4 + 2], c2.h, az);
    ar = fdot2(W[1][4 * p4 + 2], c2.h, ar);
    ah = fdot2(W[2][4 * p4 + 2], c2.h, ah);
    az = fdot2(W[0][4 * p4 + 3], c3.h, az);
    ar = fdot2(W[1][4 * p4 + 3], c3.h, ar);
    ah = fdot2(W[2][4 * p4 + 3], c3.h, ah);
  }
}

// K1: gates_x[b,t,:] = emb[ids[b,t]] @ w_ih + b_ih, stored fp16.
// wg g at iteration m handles (b=(g+m)&255, t=m): balanced across wgs.
__global__ __launch_bounds__(512, 2) void gates_kernel(
    const int* __restrict__ ids, const int* __restrict__ lens,
    const float* __restrict__ emb, const float* __restrict__ w_ih,
    const float* __restrict__ b_ih, __half* __restrict__ gates) {
  __shared__ float gpart[2][3][256];
  __shared__ __half xpk[2][256];
  __shared__ int len_s[256];
  const int tid = threadIdx.x;
  const int g = blockIdx.x;
  const int kc = tid >> 8;
  const int j = tid & 255;

  half2v W[3][64];
  load_w(w_ih, kc, j, W);

  float bi0 = 0.f, bi1 = 0.f, bi2 = 0.f;
  if (tid < 256) {
    len_s[j] = lens[j];
    bi0 = b_ih[j];
    bi1 = b_ih[256 + j];
    bi2 = b_ih[512 + j];
    int id0 = ids[(size_t)g * T_];
    xpk[0][j] = (__half)emb[(size_t)id0 * H_ + j];
  }
  __syncthreads();

  int idNext = ids[(size_t)((g + 1) & 255) * T_ + 1];  // id for m=1 (T_>1)
  for (int m = 0; m < T_; ++m) {
    const int b = (g + m) & 255;
    const bool valid = (m < len_s[b]);
    const int bn = (g + m + 1) & 255;
    const bool validN = (m + 1 < T_) && ((m + 1) < len_s[bn]);
    const int cur = m & 1, nxt = cur ^ 1;

    float xv = 0.f;
    if (tid < 256 && validN) {
      xv = emb[(size_t)idNext * H_ + j];
    }
    int idN2 = 0;
    if (m + 2 < T_) idN2 = ids[(size_t)((g + m + 2) & 255) * T_ + (m + 2)];

    if (valid) {
      float az = 0.f, ar = 0.f, ah = 0.f;
      const unsigned int* xp = (const unsigned int*)&xpk[cur][0];
      dot_phase(W, xp, kc, az, ar, ah);
      gpart[kc][0][j] = az;
      gpart[kc][1][j] = ar;
      gpart[kc][2][j] = ah;
    }
    if (tid < 256 && validN) xpk[nxt][j] = (__half)xv;
    __syncthreads();
    if (valid && tid < 256) {
      size_t base = ((size_t)b * T_ + m) * G3 + j;
      gates[base]       = (__half)(gpart[0][0][j] + gpart[1][0][j] + bi0);
      gates[base + 256] = (__half)(gpart[0][1][j] + gpart[1][1][j] + bi1);
      gates[base + 512] = (__half)(gpart[0][2][j] + gpart[1][2][j] + bi2);
    }
    idNext = idN2;
    __syncthreads();
  }
}

// K2: sequential GRU recurrence, one wg per batch row, w_hh register-resident.
__global__ __launch_bounds__(512, 2) void rec_kernel(
    const int* __restrict__ lens, const float* __restrict__ w_hh,
    const float* __restrict__ b_hh, const __half* __restrict__ gates,
    float* __restrict__ hfin) {
  __shared__ float rpart[2][3][256];
  __shared__ float h_s[256];
  __shared__ __half hpk[256];
  const int tid = threadIdx.x;
  const int b = blockIdx.x;
  const int kc = tid >> 8;
  const int j = tid & 255;

  half2v W[3][64];
  load_w(w_hh, kc, j, W);

  const int len = lens[b];
  float bh0 = 0.f, bh1 = 0.f, bh2 = 0.f;
  if (tid < 256) {
    bh0 = b_hh[j];
    bh1 = b_hh[256 + j];
    bh2 = b_hh[512 + j];
    h_s[j] = 0.f;
    hpk[j] = (__half)0.f;
  }
  __syncthreads();

  const __half* gp = gates + (size_t)b * T_ * G3 + j;
  for (int t = 0; t < len; ++t) {
    float gxz = 0.f, gxr = 0.f, gxh = 0.f;
    if (tid < 256) {  // prefetch gates for this step; consumed after barrier
      const __half* gpt = gp + (size_t)t * G3;
      gxz = (float)gpt[0];
      gxr = (float)gpt[256];
      gxh = (float)gpt[512];
    }
    float az = 0.f, ar = 0.f, ah = 0.f;
    const unsigned int* hp = (const unsigned int*)&hpk[0];
    dot_phase(W, hp, kc, az, ar, ah);
    rpart[kc][0][j] = az;
    rpart[kc][1][j] = ar;
    rpart[kc][2][j] = ah;
    __syncthreads();
    if (tid < 256) {
      float rz = rpart[0][0][j] + rpart[1][0][j] + bh0;
      float rr = rpart[0][1][j] + rpart[1][1][j] + bh1;
      float rh = rpart[0][2][j] + rpart[1][2][j] + bh2;
      float z = sigmoidf_(gxz + rz);
      float r = sigmoidf_(gxr + rr);
      float hhv = tanhf_(gxh + r * rh);
      float hn = z * h_s[j] + (1.f - z) * hhv;
      h_s[j] = hn;
      hpk[j] = (__half)hn;
    }
    __syncthreads();
  }
  if (tid < 256) hfin[(size_t)b * H_ + j] = h_s[j];
}

// K3: logits[256 x 50001] = hfin @ emb^T, fp32 tiled GEMM.
// Tile: 64 b-rows x 128 n-cols per wg; thread computes 4x8.
__global__ __launch_bounds__(256) void logits_kernel(
    const float* __restrict__ hfin, const float* __restrict__ emb,
    float* __restrict__ out) {
  __shared__ float hsT[32][64];
  __shared__ float esT[32][132];  // padded row to spread banks
  const int tid = threadIdx.x;
  const int tx = tid & 15, ty = tid >> 4;
  const int n0 = blockIdx.x * 128;
  const int b0 = blockIdx.y * 64;
  float acc[4][8];
#pragma unroll
  for (int i = 0; i < 4; ++i)
#pragma unroll
    for (int q = 0; q < 8; ++q) acc[i][q] = 0.f;

  for (int k0 = 0; k0 < H_; k0 += 32) {
    {  // stage h transposed: 8 elements per thread
      int i = tid * 8;
      int r = i >> 5;
      int c = i & 31;
      const float* src = hfin + (size_t)(b0 + r) * H_ + k0 + c;
      float4 a0 = *(const float4*)(src);
      float4 a1 = *(const float4*)(src + 4);
      hsT[c + 0][r] = a0.x; hsT[c + 1][r] = a0.y;
      hsT[c + 2][r] = a0.z; hsT[c + 3][r] = a0.w;
      hsT[c + 4][r] = a1.x; hsT[c + 5][r] = a1.y;
      hsT[c + 6][r] = a1.z; hsT[c + 7][r] = a1.w;
    }
    {  // stage emb transposed: 16 elements per thread
      int r = tid >> 1;
      int c = (tid & 1) * 16;
      int n = n0 + r;
      float4 e0 = {0, 0, 0, 0}, e1 = {0, 0, 0, 0}, e2 = {0, 0, 0, 0}, e3 = {0, 0, 0, 0};
      if (n < NV) {
        const float* src = emb + (size_t)n * H_ + k0 + c;
        e0 = *(const float4*)(src);
        e1 = *(const float4*)(src + 4);
        e2 = *(const float4*)(src + 8);
        e3 = *(const float4*)(src + 12);
      }
      esT[c + 0][r] = e0.x;  esT[c + 1][r] = e0.y;
      esT[c + 2][r] = e0.z;  esT[c + 3][r] = e0.w;
      esT[c + 4][r] = e1.x;  esT[c + 5][r] = e1.y;
      esT[c + 6][r] = e1.z;  esT[c + 7][r] = e1.w;
      esT[c + 8][r] = e2.x;  esT[c + 9][r] = e2.y;
      esT[c + 10][r] = e2.z; esT[c + 11][r] = e2.w;
      esT[c + 12][r] = e3.x; esT[c + 13][r] = e3.y;
      esT[c + 14][r] = e3.z; esT[c + 15][r] = e3.w;
    }
    __syncthreads();
#pragma unroll
    for (int kk = 0; kk < 32; ++kk) {
      float4 hv = *(const float4*)&hsT[kk][ty * 4];
      float4 ea = *(const float4*)&esT[kk][tx * 8];
      float4 eb = *(const float4*)&esT[kk][tx * 8 + 4];
#define ROWFMA(i, hc)                                                     \
  acc[i][0] += hc * ea.x; acc[i][1] += hc * ea.y;                         \
  acc[i][2] += hc * ea.z; acc[i][3] += hc * ea.w;                         \
  acc[i][4] += hc * eb.x; acc[i][5] += hc * eb.y;                         \
  acc[i][6] += hc * eb.z; acc[i][7] += hc * eb.w;
      ROWFMA(0, hv.x)
      ROWFMA(1, hv.y)
      ROWFMA(2, hv.z)
      ROWFMA(3, hv.w)
#undef ROWFMA
    }
    __syncthreads();
  }
#pragma unroll
  for (int i = 0; i < 4; ++i) {
    int bb = b0 + ty * 4 + i;
    float* op = out + (size_t)bb * NV + n0 + tx * 8;
#pragma unroll
    for (int q = 0; q < 8; ++q) {
      int n = n0 + tx * 8 + q;
      if (n < NV) op[q] = acc[i][q];
    }
  }
}

extern "C" void kernel_launch(void* const* d_in, const int* in_sizes, int n_in,
                              void* d_out, int out_size, void* d_ws, size_t ws_size,
                              hipStream_t stream) {
  const int* ids = (const int*)d_in[0];
  const int* lens = (const int*)d_in[1];
  const float* emb = (const float*)d_in[2];
  const float* w_ih = (const float*)d_in[3];
  const float* w_hh = (const float*)d_in[4];
  const float* b_ih = (const float*)d_in[5];
  const float* b_hh = (const float*)d_in[6];
  float* out = (float*)d_out;

  __half* gates = (__half*)d_ws;
  float* hfin = (float*)((char*)d_ws + (size_t)B_ * T_ * G3 * sizeof(__half));

  gates_kernel<<<dim3(B_), dim3(512), 0, stream>>>(ids, lens, emb, w_ih, b_ih, gates);
  rec_kernel<<<dim3(B_), dim3(512), 0, stream>>>(lens, w_hh, b_hh, gates, hfin);
  logits_kernel<<<dim3((NV + 127) / 128, B_ / 64), dim3(256), 0, stream>>>(hfin, emb, out);
}

// Round 2
// 601.541 us; speedup vs baseline: 1.3486x; 1.3486x over previous
//
#include <hip/hip_runtime.h>
#include <hip/hip_fp16.h>

#define B_ 256
#define T_ 200
#define H_ 256
#define G3 768            // 3*H
#define NV 50001          // V+1
#define KP 128            // K/2 half2 pairs

using half2v = __attribute__((ext_vector_type(2))) _Float16;

union U32H2 { unsigned int u; half2v h; };

__device__ __forceinline__ float fdot2(half2v a, half2v b, float c) {
  return __builtin_amdgcn_fdot2(a, b, c, false);
}
__device__ __forceinline__ float sigmoidf_(float x) {
  return 1.f / (1.f + __expf(-x));
}
__device__ __forceinline__ float tanhf_(float x) {
  float ax = fabsf(x);
  float e = __expf(-2.f * ax);
  float t = (1.f - e) / (1.f + e);
  return copysignf(t, x);
}

// Pre-pack: w (fp32 [256 x 768]) -> K-pair-packed fp16: out[p*768+col] =
// (w[2p][col], w[2p+1][col]). Two matrices, 98304 uints each.
__global__ __launch_bounds__(256) void pack_w(
    const float* __restrict__ wih, const float* __restrict__ whh,
    unsigned int* __restrict__ out) {
  int idx = blockIdx.x * 256 + threadIdx.x;  // 0 .. 2*98304-1
  int m = idx / (KP * G3);
  int r = idx - m * (KP * G3);
  int p = r / G3;
  int col = r - p * G3;
  const float* w = m ? whh : wih;
  U32H2 u;
  u.h.x = (_Float16)w[(size_t)(2 * p) * G3 + col];
  u.h.y = (_Float16)w[(size_t)(2 * p + 1) * G3 + col];
  out[idx] = u.u;
}

// Thread owns column `col` of packed weights, full K: 128 half2 regs.
__device__ __forceinline__ void load_w768(const unsigned int* __restrict__ wp,
                                          int col, half2v W[KP]) {
#pragma unroll
  for (int p = 0; p < KP; ++p) {
    U32H2 u;
    u.u = wp[(size_t)p * G3 + col];
    W[p] = u.h;
  }
}

// Full-K dot: 128 fdot2 against packed fp16 vector in LDS (broadcast reads).
__device__ __forceinline__ float dot768(const half2v (&W)[KP],
                                        const unsigned int* __restrict__ x) {
  float a0 = 0.f, a1 = 0.f;
#pragma unroll
  for (int p4 = 0; p4 < KP / 4; ++p4) {
    uint4 v = ((const uint4*)x)[p4];
    U32H2 c0, c1, c2, c3;
    c0.u = v.x; c1.u = v.y; c2.u = v.z; c3.u = v.w;
    a0 = fdot2(W[4 * p4 + 0], c0.h, a0);
    a1 = fdot2(W[4 * p4 + 1], c1.h, a1);
    a0 = fdot2(W[4 * p4 + 2], c2.h, a0);
    a1 = fdot2(W[4 * p4 + 3], c3.h, a1);
  }
  return a0 + a1;
}

// K1: gates_x[b,t,col] = emb[ids[b,t]] . w_ih[:,col] + b_ih[col], fp16 out.
// wg g at iteration m handles (b=(g+m)&255, t=m): balanced, no atomics.
__global__ __launch_bounds__(768, 3) void gates_kernel(
    const int* __restrict__ ids, const int* __restrict__ lens,
    const float* __restrict__ emb, const unsigned int* __restrict__ wih_p,
    const float* __restrict__ b_ih, __half* __restrict__ gates) {
  __shared__ __half xpk[2][256];
  __shared__ int len_s[256];
  const int tid = threadIdx.x;
  const int g = blockIdx.x;

  half2v W[KP];
  load_w768(wih_p, tid, W);
  const float bi = b_ih[tid];

  if (tid < 256) {
    len_s[tid] = lens[tid];
    int id0 = ids[(size_t)g * T_];
    xpk[0][tid] = (__half)emb[(size_t)id0 * H_ + tid];
  }
  __syncthreads();

  int idNext = ids[(size_t)((g + 1) & 255) * T_ + 1];
  for (int m = 0; m < T_; ++m) {
    const int b = (g + m) & 255;
    const bool valid = (m < len_s[b]);
    const int bn = (g + m + 1) & 255;
    const bool validN = (m + 1 < T_) && ((m + 1) < len_s[bn]);
    const int cur = m & 1, nxt = cur ^ 1;

    float xv = 0.f;
    if (tid < 256 && validN) xv = emb[(size_t)idNext * H_ + tid];
    int idN2 = (m + 2 < T_) ? ids[(size_t)((g + m + 2) & 255) * T_ + (m + 2)] : 0;

    if (valid) {
      float d = dot768(W, (const unsigned int*)&xpk[cur][0]);
      gates[((size_t)b * T_ + m) * G3 + tid] = (__half)(d + bi);
    }
    if (tid < 256 && validN) xpk[nxt][tid] = (__half)xv;
    idNext = idN2;
    __syncthreads();
  }
}

// K2: sequential GRU recurrence, one wg per batch row, w_hh register-resident.
__global__ __launch_bounds__(768, 3) void rec_kernel(
    const int* __restrict__ lens, const unsigned int* __restrict__ whh_p,
    const float* __restrict__ b_hh, const __half* __restrict__ gates,
    float* __restrict__ hfin) {
  __shared__ float rec[G3];
  __shared__ __half hpk[256];
  const int tid = threadIdx.x;
  const int b = blockIdx.x;

  half2v W[KP];
  load_w768(whh_p, tid, W);

  const int len = lens[b];
  float bh0 = 0.f, bh1 = 0.f, bh2 = 0.f;
  float h = 0.f;
  if (tid < 256) {
    bh0 = b_hh[tid];
    bh1 = b_hh[256 + tid];
    bh2 = b_hh[512 + tid];
    hpk[tid] = (__half)0.f;
  }
  __syncthreads();

  const __half* gp = gates + (size_t)b * T_ * G3 + tid;
  for (int t = 0; t < len; ++t) {
    float gxz = 0.f, gxr = 0.f, gxh = 0.f;
    if (tid < 256) {  // prefetch; consumed after the barrier
      const __half* gpt = gp + (size_t)t * G3;
      gxz = (float)gpt[0];
      gxr = (float)gpt[256];
      gxh = (float)gpt[512];
    }
    float d = dot768(W, (const unsigned int*)&hpk[0]);
    rec[tid] = d;
    __syncthreads();
    if (tid < 256) {
      float z = sigmoidf_(gxz + rec[tid] + bh0);
      float r = sigmoidf_(gxr + rec[256 + tid] + bh1);
      float hh = tanhf_(gxh + r * (rec[512 + tid] + bh2));
      h = z * h + (1.f - z) * hh;
      hpk[tid] = (__half)h;
    }
    __syncthreads();
  }
  if (tid < 256) hfin[(size_t)b * H_ + tid] = h;
}

// K3: logits[256 x 50001] = hfin @ emb^T, fp32 tiled GEMM (unchanged).
__global__ __launch_bounds__(256) void logits_kernel(
    const float* __restrict__ hfin, const float* __restrict__ emb,
    float* __restrict__ out) {
  __shared__ float hsT[32][64];
  __shared__ float esT[32][132];
  const int tid = threadIdx.x;
  const int tx = tid & 15, ty = tid >> 4;
  const int n0 = blockIdx.x * 128;
  const int b0 = blockIdx.y * 64;
  float acc[4][8];
#pragma unroll
  for (int i = 0; i < 4; ++i)
#pragma unroll
    for (int q = 0; q < 8; ++q) acc[i][q] = 0.f;

  for (int k0 = 0; k0 < H_; k0 += 32) {
    {
      int i = tid * 8;
      int r = i >> 5;
      int c = i & 31;
      const float* src = hfin + (size_t)(b0 + r) * H_ + k0 + c;
      float4 a0 = *(const float4*)(src);
      float4 a1 = *(const float4*)(src + 4);
      hsT[c + 0][r] = a0.x; hsT[c + 1][r] = a0.y;
      hsT[c + 2][r] = a0.z; hsT[c + 3][r] = a0.w;
      hsT[c + 4][r] = a1.x; hsT[c + 5][r] = a1.y;
      hsT[c + 6][r] = a1.z; hsT[c + 7][r] = a1.w;
    }
    {
      int r = tid >> 1;
      int c = (tid & 1) * 16;
      int n = n0 + r;
      float4 e0 = {0,0,0,0}, e1 = {0,0,0,0}, e2 = {0,0,0,0}, e3 = {0,0,0,0};
      if (n < NV) {
        const float* src = emb + (size_t)n * H_ + k0 + c;
        e0 = *(const float4*)(src);
        e1 = *(const float4*)(src + 4);
        e2 = *(const float4*)(src + 8);
        e3 = *(const float4*)(src + 12);
      }
      esT[c + 0][r] = e0.x;  esT[c + 1][r] = e0.y;
      esT[c + 2][r] = e0.z;  esT[c + 3][r] = e0.w;
      esT[c + 4][r] = e1.x;  esT[c + 5][r] = e1.y;
      esT[c + 6][r] = e1.z;  esT[c + 7][r] = e1.w;
      esT[c + 8][r] = e2.x;  esT[c + 9][r] = e2.y;
      esT[c + 10][r] = e2.z; esT[c + 11][r] = e2.w;
      esT[c + 12][r] = e3.x; esT[c + 13][r] = e3.y;
      esT[c + 14][r] = e3.z; esT[c + 15][r] = e3.w;
    }
    __syncthreads();
#pragma unroll
    for (int kk = 0; kk < 32; ++kk) {
      float4 hv = *(const float4*)&hsT[kk][ty * 4];
      float4 ea = *(const float4*)&esT[kk][tx * 8];
      float4 eb = *(const float4*)&esT[kk][tx * 8 + 4];
#define ROWFMA(i, hc)                                                     \
  acc[i][0] += hc * ea.x; acc[i][1] += hc * ea.y;                         \
  acc[i][2] += hc * ea.z; acc[i][3] += hc * ea.w;                         \
  acc[i][4] += hc * eb.x; acc[i][5] += hc * eb.y;                         \
  acc[i][6] += hc * eb.z; acc[i][7] += hc * eb.w;
      ROWFMA(0, hv.x)
      ROWFMA(1, hv.y)
      ROWFMA(2, hv.z)
      ROWFMA(3, hv.w)
#undef ROWFMA
    }
    __syncthreads();
  }
#pragma unroll
  for (int i = 0; i < 4; ++i) {
    int bb = b0 + ty * 4 + i;
    float* op = out + (size_t)bb * NV + n0 + tx * 8;
#pragma unroll
    for (int q = 0; q < 8; ++q) {
      int n = n0 + tx * 8 + q;
      if (n < NV) op[q] = acc[i][q];
    }
  }
}

extern "C" void kernel_launch(void* const* d_in, const int* in_sizes, int n_in,
                              void* d_out, int out_size, void* d_ws, size_t ws_size,
                              hipStream_t stream) {
  const int* ids = (const int*)d_in[0];
  const int* lens = (const int*)d_in[1];
  const float* emb = (const float*)d_in[2];
  const float* w_ih = (const float*)d_in[3];
  const float* w_hh = (const float*)d_in[4];
  const float* b_ih = (const float*)d_in[5];
  const float* b_hh = (const float*)d_in[6];
  float* out = (float*)d_out;

  char* ws = (char*)d_ws;
  __half* gates = (__half*)ws;                                   // 78.6 MB
  float* hfin = (float*)(ws + (size_t)B_ * T_ * G3 * sizeof(__half));
  unsigned int* wpack = (unsigned int*)(ws + (size_t)B_ * T_ * G3 * sizeof(__half)
                                        + (size_t)B_ * H_ * sizeof(float));
  unsigned int* wih_p = wpack;                                   // 393 KB
  unsigned int* whh_p = wpack + (size_t)KP * G3;                 // 393 KB

  pack_w<<<dim3(2 * KP * G3 / 256), dim3(256), 0, stream>>>(w_ih, w_hh, wpack);
  gates_kernel<<<dim3(B_), dim3(768), 0, stream>>>(ids, lens, emb, wih_p, b_ih, gates);
  rec_kernel<<<dim3(B_), dim3(768), 0, stream>>>(lens, whh_p, b_hh, gates, hfin);
  logits_kernel<<<dim3((NV + 127) / 128, B_ / 64), dim3(256), 0, stream>>>(hfin, emb, out);
}